// Round 1
// baseline (469.193 us; speedup 1.0000x reference)
//
#include <hip/hip_runtime.h>
#include <stdint.h>

typedef unsigned short u16;
typedef __bf16 bf16x8 __attribute__((ext_vector_type(8)));
typedef float f32x4 __attribute__((ext_vector_type(4)));
typedef __attribute__((address_space(1))) const unsigned int as1_u32;
typedef __attribute__((address_space(3))) unsigned int as3_u32;

#define SEQ 4096
#define HID 1152
#define NH 16
#define HD 72

__device__ __forceinline__ void gload_lds16(const void* g, void* l) {
  __builtin_amdgcn_global_load_lds((as1_u32*)g, (as3_u32*)l, 16, 0, 0);
}
__device__ __forceinline__ u16 f2bf(float f) {
  __bf16 h = (__bf16)f;
  return __builtin_bit_cast(u16, h);
}
__device__ __forceinline__ float bf2f(u16 u) {
  unsigned int x = ((unsigned int)u) << 16;
  return __builtin_bit_cast(float, x);
}

// ---------------- cast X fp32 -> bf16 ----------------
__global__ void cvt_x(const float* __restrict__ X, u16* __restrict__ Xb, int n4) {
  int i = blockIdx.x * blockDim.x + threadIdx.x;
  if (i < n4) {
    float4 v = *(const float4*)(X + (size_t)i * 4);
    unsigned int lo = f2bf(v.x) | ((unsigned int)f2bf(v.y) << 16);
    unsigned int hi = f2bf(v.z) | ((unsigned int)f2bf(v.w) << 16);
    *(uint2*)(Xb + (size_t)i * 4) = make_uint2(lo, hi);
  }
}

// ---------------- transpose + cast W (1152x1152 each) ----------------
// src [k][n] fp32 -> dst [n][k] bf16.  z: 0..2 -> Wq/Wk/Wv into Wt, 3 -> Wo into Wot
__global__ void transpose_w(const float* __restrict__ Wq, const float* __restrict__ Wk,
                            const float* __restrict__ Wv, const float* __restrict__ Wo,
                            u16* __restrict__ Wt, u16* __restrict__ Wot) {
  __shared__ __align__(16) float t[32][33];
  int z = blockIdx.z;
  const float* src = (z == 0) ? Wq : (z == 1) ? Wk : (z == 2) ? Wv : Wo;
  u16* dst = (z < 3) ? (Wt + (size_t)z * HID * HID) : Wot;
  int tx = threadIdx.x & 31, ty = threadIdx.x >> 5;  // 32 x 8
  int c0 = blockIdx.x * 32, r0 = blockIdx.y * 32;
#pragma unroll
  for (int i = 0; i < 4; i++)
    t[ty + i * 8][tx] = src[(size_t)(r0 + ty + i * 8) * HID + c0 + tx];
  __syncthreads();
#pragma unroll
  for (int i = 0; i < 4; i++)
    dst[(size_t)(c0 + ty + i * 8) * HID + r0 + tx] = f2bf(t[tx][ty + i * 8]);
}

// ---------------- bf16 GEMM  C[M][N] = A[M][K] * Bt[N][K]^T ----------------
// 128x128 tile, BK=64, 4 waves (each 64x64), 16x16x32 MFMA, swizzled LDS.
template <int OUTBF16>
__global__ __launch_bounds__(256, 2) void gemm_bt(const u16* __restrict__ A,
                                                  const u16* __restrict__ Bt,
                                                  void* __restrict__ Cout,
                                                  int M, int N, int K) {
  __shared__ __align__(16) u16 lds[2][2][128 * 64];
  const int tid = threadIdx.x;
  const int wave = tid >> 6, lane = tid & 63;
  const int l15 = lane & 15, l4 = lane >> 4;
  const size_t bm = (size_t)blockIdx.x * 128, bn = (size_t)blockIdx.y * 128;
  const int wm = (wave >> 1) * 64, wn = (wave & 1) * 64;
  const int nt = K >> 6;

  f32x4 acc[4][4] = {};

  auto stage = [&](int buf, int kt) {
    const int k0 = kt << 6;
#pragma unroll
    for (int r = 0; r < 4; r++) {
      int idx = (r << 8) + tid;
      int m = idx >> 3, j = idx & 7;
      int js = j ^ (m & 7);
      void* ldsA = (void*)&lds[buf][0][(size_t)((r << 8) + (wave << 6)) * 8];
      void* ldsB = (void*)&lds[buf][1][(size_t)((r << 8) + (wave << 6)) * 8];
      gload_lds16(A + (bm + m) * (size_t)K + k0 + js * 8, ldsA);
      gload_lds16(Bt + (bn + m) * (size_t)K + k0 + js * 8, ldsB);
    }
  };

  stage(0, 0);
  for (int t = 0; t < nt; t++) {
    __syncthreads();  // staged tile t visible (drains vmcnt); all waves done reading buf t+1 from t-1
    if (t + 1 < nt) stage((t + 1) & 1, t + 1);
    const u16* As = &lds[t & 1][0][0];
    const u16* Bs = &lds[t & 1][1][0];
#pragma unroll
    for (int kk = 0; kk < 2; kk++) {
      bf16x8 af[4], bfr[4];
      int slot = (kk << 2) + l4;
#pragma unroll
      for (int mi = 0; mi < 4; mi++) {
        int m = wm + (mi << 4) + l15;
        af[mi] = *(const bf16x8*)&As[m * 64 + ((slot ^ (m & 7)) << 3)];
      }
#pragma unroll
      for (int ni = 0; ni < 4; ni++) {
        int n = wn + (ni << 4) + l15;
        bfr[ni] = *(const bf16x8*)&Bs[n * 64 + ((slot ^ (n & 7)) << 3)];
      }
#pragma unroll
      for (int mi = 0; mi < 4; mi++)
#pragma unroll
        for (int ni = 0; ni < 4; ni++)
          acc[mi][ni] = __builtin_amdgcn_mfma_f32_16x16x32_bf16(af[mi], bfr[ni], acc[mi][ni], 0, 0, 0);
    }
  }

#pragma unroll
  for (int mi = 0; mi < 4; mi++)
#pragma unroll
    for (int ni = 0; ni < 4; ni++)
#pragma unroll
      for (int r = 0; r < 4; r++) {
        size_t m = bm + wm + (mi << 4) + (l4 << 2) + r;
        size_t n = bn + wn + (ni << 4) + l15;
        if (OUTBF16)
          ((u16*)Cout)[m * N + n] = f2bf(acc[mi][ni][r]);
        else
          ((float*)Cout)[m * N + n] = acc[mi][ni][r];
      }
}

// ---------------- fused RMSNorm + 2D RoPE ----------------
// C1 bf16 [4096][3456] -> Qp,Kp bf16 [h][m][128] (zero-padded 72..127),
//                         Vt bf16 [h][d:96][m] (zero-padded 72..95)
__global__ void norm_rope(const u16* __restrict__ C1, const float* __restrict__ cosv,
                          const float* __restrict__ sinv, const float* __restrict__ qsc,
                          const float* __restrict__ ksc, u16* __restrict__ Qp,
                          u16* __restrict__ Kp, u16* __restrict__ Vt) {
  const int tid = threadIdx.x;
  const int wave = tid >> 6, lane = tid & 63;
  int gw = blockIdx.x * 4 + wave;  // 0..4095
  for (int it = 0; it < 16; it++) {
    int pair = gw + it * 4096;  // 0..65535
    int n = pair >> 4, h = pair & 15;
    int j = lane;
    float q1 = 0, q2 = 0, k1 = 0, k2 = 0, v1 = 0, v2 = 0;
    int i1 = 0, i2 = 0;
    bool act = j < 36;
    if (act) {
      int half = j / 18, jj = j % 18;
      i1 = half * 36 + jj;
      i2 = i1 + 18;
      const u16* base = C1 + (size_t)n * 3456 + h * HD;
      q1 = bf2f(base[i1]);        q2 = bf2f(base[i2]);
      k1 = bf2f(base[1152 + i1]); k2 = bf2f(base[1152 + i2]);
      v1 = bf2f(base[2304 + i1]); v2 = bf2f(base[2304 + i2]);
    }
    float sq = q1 * q1 + q2 * q2, sk = k1 * k1 + k2 * k2, sv = v1 * v1 + v2 * v2;
#pragma unroll
    for (int m = 1; m < 64; m <<= 1) {
      sq += __shfl_xor(sq, m);
      sk += __shfl_xor(sk, m);
      sv += __shfl_xor(sv, m);
    }
    float rq = rsqrtf(sq / 72.0f + 1e-6f);
    float rk = rsqrtf(sk / 72.0f + 1e-6f);
    float rv = rsqrtf(sv / 72.0f + 1e-6f);
    size_t qrow = ((size_t)h * SEQ + n) * 128;
    size_t vbase = (size_t)h * 96 * SEQ + n;
    if (act) {
      float c1 = cosv[n * HD + i1], c2 = cosv[n * HD + i2];
      float s1 = sinv[n * HD + i1], s2 = sinv[n * HD + i2];
      float yq1 = q1 * rq * qsc[i1], yq2 = q2 * rq * qsc[i2];
      float yk1 = k1 * rk * ksc[i1], yk2 = k2 * rk * ksc[i2];
      Qp[qrow + i1] = f2bf(yq1 * c1 - yq2 * s1);
      Qp[qrow + i2] = f2bf(yq2 * c2 + yq1 * s2);
      Kp[qrow + i1] = f2bf(yk1 * c1 - yk2 * s1);
      Kp[qrow + i2] = f2bf(yk2 * c2 + yk1 * s2);
      Vt[vbase + (size_t)i1 * SEQ] = f2bf(v1 * rv);
      Vt[vbase + (size_t)i2 * SEQ] = f2bf(v2 * rv);
    } else {
      int d1 = j + 36;  // 72..99
      int d2 = j + 64;  // 100..127
      Qp[qrow + d1] = 0; Qp[qrow + d2] = 0;
      Kp[qrow + d1] = 0; Kp[qrow + d2] = 0;
      if (d1 < 96) Vt[vbase + (size_t)d1 * SEQ] = 0;
    }
  }
}

// ---------------- flash attention ----------------
// grid (64 q-tiles, 16 heads), 4 waves x 16 q-rows, 64-key tiles
__global__ __launch_bounds__(256, 2) void attn(const u16* __restrict__ Qp,
                                               const u16* __restrict__ Kp,
                                               const u16* __restrict__ Vt,
                                               u16* __restrict__ AO) {
  __shared__ __align__(16) u16 Ks[64 * 128];
  __shared__ __align__(16) u16 Vs[96 * 64];
  __shared__ __align__(16) u16 Ps[4][1024];
  const int tid = threadIdx.x;
  const int wave = tid >> 6, lane = tid & 63;
  const int l15 = lane & 15, l4 = lane >> 4;
  const int h = blockIdx.y;
  const int q0 = blockIdx.x * 64 + wave * 16;

  bf16x8 aq[3];
  const u16* qbase = Qp + ((size_t)h * SEQ + q0 + l15) * 128;
#pragma unroll
  for (int kk = 0; kk < 3; kk++) aq[kk] = *(const bf16x8*)(qbase + kk * 32 + l4 * 8);

  f32x4 acc[6] = {};
  float mi_[4], li_[4];
#pragma unroll
  for (int r = 0; r < 4; r++) { mi_[r] = -1e30f; li_[r] = 0.0f; }

  for (int k0 = 0; k0 < SEQ; k0 += 64) {
    // stage K tile: 64 rows x 16 slots (swizzled source, linear LDS)
#pragma unroll
    for (int r = 0; r < 4; r++) {
      int idx = (r << 8) + tid;
      int m = idx >> 4, j = idx & 15;
      int js = j ^ (m & 15);
      gload_lds16(Kp + ((size_t)h * SEQ + k0 + m) * 128 + js * 8,
                  (void*)&Ks[(size_t)((r << 8) + (wave << 6)) * 8]);
    }
    // stage V tile: 96 rows x 8 slots
#pragma unroll
    for (int r = 0; r < 3; r++) {
      int idx = (r << 8) + tid;
      int d = idx >> 3, j = idx & 7;
      int js = j ^ (d & 7);
      gload_lds16(Vt + ((size_t)h * 96 + d) * SEQ + k0 + js * 8,
                  (void*)&Vs[(size_t)((r << 8) + (wave << 6)) * 8]);
    }
    __syncthreads();

    // S = Q * K^T (16 x 64 per wave)
    f32x4 s[4] = {};
#pragma unroll
    for (int kk = 0; kk < 3; kk++) {
      int slot = (kk << 2) + l4;
#pragma unroll
      for (int nf = 0; nf < 4; nf++) {
        int krow = (nf << 4) + l15;
        bf16x8 bk = *(const bf16x8*)&Ks[krow * 128 + ((slot ^ (krow & 15)) << 3)];
        s[nf] = __builtin_amdgcn_mfma_f32_16x16x32_bf16(aq[kk], bk, s[nf], 0, 0, 0);
      }
    }
    // online softmax (rows replicated over the 16-lane column group)
    float scl[4];
#pragma unroll
    for (int r = 0; r < 4; r++) {
      float v = fmaxf(fmaxf(s[0][r], s[1][r]), fmaxf(s[2][r], s[3][r]));
      v = fmaxf(v, __shfl_xor(v, 1));
      v = fmaxf(v, __shfl_xor(v, 2));
      v = fmaxf(v, __shfl_xor(v, 4));
      v = fmaxf(v, __shfl_xor(v, 8));
      float mnew = fmaxf(mi_[r], v);
      scl[r] = __expf(mi_[r] - mnew);
      mi_[r] = mnew;
      float rsum = 0.f;
#pragma unroll
      for (int nf = 0; nf < 4; nf++) {
        float p = __expf(s[nf][r] - mnew);
        s[nf][r] = p;
        rsum += p;
      }
      rsum += __shfl_xor(rsum, 1);
      rsum += __shfl_xor(rsum, 2);
      rsum += __shfl_xor(rsum, 4);
      rsum += __shfl_xor(rsum, 8);
      li_[r] = li_[r] * scl[r] + rsum;
    }
    // P -> LDS (bf16, swizzled rows so PV a-frag read is conflict-free)
#pragma unroll
    for (int nf = 0; nf < 4; nf++)
#pragma unroll
      for (int r = 0; r < 4; r++) {
        int row = (l4 << 2) + r;
        int col = (nf << 4) + l15;
        Ps[wave][row * 64 + (((col >> 3) ^ (row & 7)) << 3) + (col & 7)] = f2bf(s[nf][r]);
      }
    // rescale accumulator
#pragma unroll
    for (int ni = 0; ni < 6; ni++)
#pragma unroll
      for (int r = 0; r < 4; r++) acc[ni][r] *= scl[r];
    // PV: out(16 x 96) += P(16 x 64) * V(64 x 96)
#pragma unroll
    for (int kk = 0; kk < 2; kk++) {
      int slot = (kk << 2) + l4;
      bf16x8 pa = *(const bf16x8*)&Ps[wave][l15 * 64 + ((slot ^ (l15 & 7)) << 3)];
#pragma unroll
      for (int ni = 0; ni < 6; ni++) {
        int d = (ni << 4) + l15;
        bf16x8 bv = *(const bf16x8*)&Vs[d * 64 + ((slot ^ (d & 7)) << 3)];
        acc[ni] = __builtin_amdgcn_mfma_f32_16x16x32_bf16(pa, bv, acc[ni], 0, 0, 0);
      }
    }
    __syncthreads();
  }
  // epilogue
#pragma unroll
  for (int r = 0; r < 4; r++) {
    float inv = 1.0f / li_[r];
    int q = q0 + (l4 << 2) + r;
#pragma unroll
    for (int ni = 0; ni < 6; ni++) {
      int d = (ni << 4) + l15;
      if (d < HD) AO[(size_t)q * HID + h * HD + d] = f2bf(acc[ni][r] * inv);
    }
  }
}

extern "C" void kernel_launch(void* const* d_in, const int* in_sizes, int n_in,
                              void* d_out, int out_size, void* d_ws, size_t ws_size,
                              hipStream_t stream) {
  const float* X = (const float*)d_in[0];
  const float* cosv = (const float*)d_in[1];
  const float* sinv = (const float*)d_in[2];
  const float* Wq = (const float*)d_in[3];
  const float* Wk = (const float*)d_in[4];
  const float* Wv = (const float*)d_in[5];
  const float* Wo = (const float*)d_in[6];
  const float* qsc = (const float*)d_in[7];
  const float* ksc = (const float*)d_in[8];
  float* out = (float*)d_out;

  uint8_t* ws = (uint8_t*)d_ws;
  u16* Xb  = (u16*)(ws);                 //  9,437,184 B  (4096x1152 bf16)
  u16* Wt  = (u16*)(ws + 9437184);       //  7,962,624 B  (3456x1152 bf16)
  u16* Wot = (u16*)(ws + 17399808);      //  2,654,208 B  (1152x1152 bf16)
  u16* C1  = (u16*)(ws + 20054016);      // 28,311,552 B  (4096x3456 bf16)
  u16* Qp  = (u16*)(ws + 48365568);      // 16,777,216 B  (16x4096x128 bf16)
  u16* Kp  = (u16*)(ws + 65142784);      // 16,777,216 B
  u16* Vt  = (u16*)(ws + 81920000);      // 12,582,912 B  (16x96x4096 bf16)
  u16* AO  = Xb;                         // reuse: Xb consumed by GEMM1 before attn writes

  cvt_x<<<4608, 256, 0, stream>>>(X, Xb, (SEQ * HID) / 4);
  transpose_w<<<dim3(36, 36, 4), 256, 0, stream>>>(Wq, Wk, Wv, Wo, Wt, Wot);
  gemm_bt<1><<<dim3(32, 27), 256, 0, stream>>>(Xb, Wt, (void*)C1, SEQ, 3456, HID);
  norm_rope<<<1024, 256, 0, stream>>>(C1, cosv, sinv, qsc, ksc, Qp, Kp, Vt);
  attn<<<dim3(64, 16), 256, 0, stream>>>(Qp, Kp, Vt, AO);
  gemm_bt<0><<<dim3(32, 9), 256, 0, stream>>>(AO, Wot, (void*)out, SEQ, HID, HID);
}

// Round 2
// 343.781 us; speedup vs baseline: 1.3648x; 1.3648x over previous
//
#include <hip/hip_runtime.h>
#include <stdint.h>

typedef unsigned short u16;
typedef __bf16 bf16x8 __attribute__((ext_vector_type(8)));
typedef float f32x4 __attribute__((ext_vector_type(4)));
typedef __attribute__((address_space(1))) const unsigned int as1_u32;
typedef __attribute__((address_space(3))) unsigned int as3_u32;

#define SEQ 4096
#define HID 1152
#define NH 16
#define HD 72

__device__ __forceinline__ void gload_lds16(const void* g, void* l) {
  __builtin_amdgcn_global_load_lds((as1_u32*)g, (as3_u32*)l, 16, 0, 0);
}
__device__ __forceinline__ u16 f2bf(float f) {
  __bf16 h = (__bf16)f;
  return __builtin_bit_cast(u16, h);
}
__device__ __forceinline__ float bf2f(u16 u) {
  unsigned int x = ((unsigned int)u) << 16;
  return __builtin_bit_cast(float, x);
}

// ---------------- cast X fp32 -> bf16 ----------------
__global__ void cvt_x(const float* __restrict__ X, u16* __restrict__ Xb, int n4) {
  int i = blockIdx.x * blockDim.x + threadIdx.x;
  if (i < n4) {
    float4 v = *(const float4*)(X + (size_t)i * 4);
    unsigned int lo = f2bf(v.x) | ((unsigned int)f2bf(v.y) << 16);
    unsigned int hi = f2bf(v.z) | ((unsigned int)f2bf(v.w) << 16);
    *(uint2*)(Xb + (size_t)i * 4) = make_uint2(lo, hi);
  }
}

// ---------------- transpose + cast W (1152x1152 each) ----------------
__global__ void transpose_w(const float* __restrict__ Wq, const float* __restrict__ Wk,
                            const float* __restrict__ Wv, const float* __restrict__ Wo,
                            u16* __restrict__ Wt, u16* __restrict__ Wot) {
  __shared__ __align__(16) float t[32][33];
  int z = blockIdx.z;
  const float* src = (z == 0) ? Wq : (z == 1) ? Wk : (z == 2) ? Wv : Wo;
  u16* dst = (z < 3) ? (Wt + (size_t)z * HID * HID) : Wot;
  int tx = threadIdx.x & 31, ty = threadIdx.x >> 5;  // 32 x 8
  int c0 = blockIdx.x * 32, r0 = blockIdx.y * 32;
#pragma unroll
  for (int i = 0; i < 4; i++)
    t[ty + i * 8][tx] = src[(size_t)(r0 + ty + i * 8) * HID + c0 + tx];
  __syncthreads();
#pragma unroll
  for (int i = 0; i < 4; i++)
    dst[(size_t)(c0 + ty + i * 8) * HID + r0 + tx] = f2bf(t[tx][ty + i * 8]);
}

// ---------------- bf16 GEMM  C[M][N] = A[M][K] * Bt[N][K]^T ----------------
template <int OUTBF16>
__global__ __launch_bounds__(256, 2) void gemm_bt(const u16* __restrict__ A,
                                                  const u16* __restrict__ Bt,
                                                  void* __restrict__ Cout,
                                                  int M, int N, int K) {
  __shared__ __align__(16) u16 lds[2][2][128 * 64];
  const int tid = threadIdx.x;
  const int wave = tid >> 6, lane = tid & 63;
  const int l15 = lane & 15, l4 = lane >> 4;
  const size_t bm = (size_t)blockIdx.x * 128, bn = (size_t)blockIdx.y * 128;
  const int wm = (wave >> 1) * 64, wn = (wave & 1) * 64;
  const int nt = K >> 6;

  f32x4 acc[4][4] = {};

  auto stage = [&](int buf, int kt) {
    const int k0 = kt << 6;
#pragma unroll
    for (int r = 0; r < 4; r++) {
      int idx = (r << 8) + tid;
      int m = idx >> 3, j = idx & 7;
      int js = j ^ (m & 7);
      void* ldsA = (void*)&lds[buf][0][(size_t)((r << 8) + (wave << 6)) * 8];
      void* ldsB = (void*)&lds[buf][1][(size_t)((r << 8) + (wave << 6)) * 8];
      gload_lds16(A + (bm + m) * (size_t)K + k0 + js * 8, ldsA);
      gload_lds16(Bt + (bn + m) * (size_t)K + k0 + js * 8, ldsB);
    }
  };

  stage(0, 0);
  for (int t = 0; t < nt; t++) {
    __syncthreads();
    if (t + 1 < nt) stage((t + 1) & 1, t + 1);
    const u16* As = &lds[t & 1][0][0];
    const u16* Bs = &lds[t & 1][1][0];
#pragma unroll
    for (int kk = 0; kk < 2; kk++) {
      bf16x8 af[4], bfr[4];
      int slot = (kk << 2) + l4;
#pragma unroll
      for (int mi = 0; mi < 4; mi++) {
        int m = wm + (mi << 4) + l15;
        af[mi] = *(const bf16x8*)&As[m * 64 + ((slot ^ (m & 7)) << 3)];
      }
#pragma unroll
      for (int ni = 0; ni < 4; ni++) {
        int n = wn + (ni << 4) + l15;
        bfr[ni] = *(const bf16x8*)&Bs[n * 64 + ((slot ^ (n & 7)) << 3)];
      }
#pragma unroll
      for (int mi = 0; mi < 4; mi++)
#pragma unroll
        for (int ni = 0; ni < 4; ni++)
          acc[mi][ni] = __builtin_amdgcn_mfma_f32_16x16x32_bf16(af[mi], bfr[ni], acc[mi][ni], 0, 0, 0);
    }
  }

#pragma unroll
  for (int mi = 0; mi < 4; mi++)
#pragma unroll
    for (int ni = 0; ni < 4; ni++)
#pragma unroll
      for (int r = 0; r < 4; r++) {
        size_t m = bm + wm + (mi << 4) + (l4 << 2) + r;
        size_t n = bn + wn + (ni << 4) + l15;
        if (OUTBF16)
          ((u16*)Cout)[m * N + n] = f2bf(acc[mi][ni][r]);
        else
          ((float*)Cout)[m * N + n] = acc[mi][ni][r];
      }
}

// ---------------- fused RMSNorm + 2D RoPE (tiled, coalesced) ----------------
// grid (128 n-tiles of 32, 16 heads), 256 threads.
// C1 bf16 [4096][3456] -> Qp,Kp bf16 [h][n][128] (pad 72..127 = 0),
//                         Vt bf16 [h][80][4096]  (pad rows 72..79 = 0)
__global__ __launch_bounds__(256, 2) void norm_rope(
    const u16* __restrict__ C1, const float* __restrict__ cosv,
    const float* __restrict__ sinv, const float* __restrict__ qsc,
    const float* __restrict__ ksc, u16* __restrict__ Qp, u16* __restrict__ Kp,
    u16* __restrict__ Vt) {
  __shared__ __align__(16) u16 in_t[32 * 224];  // 32 rows x (3*72 used, stride 224)
  __shared__ __align__(16) u16 qo[32 * 128];
  __shared__ __align__(16) u16 ko[32 * 128];
  __shared__ __align__(16) u16 vo[80 * 48];  // [d][key], stride 48 (cols 0..31 used)
  const int tid = threadIdx.x;
  const int h = blockIdx.y;
  const int n0 = blockIdx.x * 32;

  // phase 1: cooperative load of the 32x216 tile (16B granules)
#pragma unroll
  for (int k = 0; k < 4; k++) {
    int g = tid + k * 256;
    if (g < 864) {
      int row = g / 27, j = g - row * 27;
      int seg = j / 9, c = (j - seg * 9) * 8;
      const u16* src = C1 + (size_t)(n0 + row) * 3456 + seg * 1152 + h * HD + c;
      *(uint4*)&in_t[row * 224 + j * 8] = *(const uint4*)src;
    }
  }
  __syncthreads();

  // phase 2: per-row (8 lanes/row) rms + rope + v-transpose
  const int r = tid >> 3, p = tid & 7;
  float sq = 0, sk = 0, sv = 0;
  auto acc8 = [&](int off, float& s) {
    uint4 v = *(const uint4*)&in_t[r * 224 + off];
    unsigned int vv[4] = {v.x, v.y, v.z, v.w};
#pragma unroll
    for (int q = 0; q < 4; q++) {
      float a = bf2f((u16)(vv[q] & 0xffff));
      float b = bf2f((u16)(vv[q] >> 16));
      s += a * a + b * b;
    }
  };
  acc8(0 + p * 8, sq);
  acc8(72 + p * 8, sk);
  acc8(144 + p * 8, sv);
  if (p == 0) { acc8(64, sq); acc8(136, sk); acc8(208, sv); }
#pragma unroll
  for (int m = 1; m < 8; m <<= 1) {
    sq += __shfl_xor(sq, m);
    sk += __shfl_xor(sk, m);
    sv += __shfl_xor(sv, m);
  }
  const float rq = rsqrtf(sq * (1.0f / 72.0f) + 1e-6f);
  const float rk = rsqrtf(sk * (1.0f / 72.0f) + 1e-6f);
  const float rv = rsqrtf(sv * (1.0f / 72.0f) + 1e-6f);

  // rope: 36 pairs (i, i+18), i in {0..17} u {36..53}; thread handles ti = p+8u
#pragma unroll
  for (int u = 0; u < 5; u++) {
    int ti = p + (u << 3);
    if (ti < 36) {
      int i1 = ti + ((ti >= 18) ? 18 : 0);
      int i2 = i1 + 18;
      const float* cb = cosv + (size_t)(n0 + r) * HD;
      const float* sb = sinv + (size_t)(n0 + r) * HD;
      float c1 = cb[i1], c2 = cb[i2], s1 = sb[i1], s2 = sb[i2];
      float q1 = bf2f(in_t[r * 224 + i1]) * rq * qsc[i1];
      float q2 = bf2f(in_t[r * 224 + i2]) * rq * qsc[i2];
      float k1 = bf2f(in_t[r * 224 + 72 + i1]) * rk * ksc[i1];
      float k2 = bf2f(in_t[r * 224 + 72 + i2]) * rk * ksc[i2];
      qo[r * 128 + i1] = f2bf(q1 * c1 - q2 * s1);
      qo[r * 128 + i2] = f2bf(q2 * c2 + q1 * s2);
      ko[r * 128 + i1] = f2bf(k1 * c1 - k2 * s1);
      ko[r * 128 + i2] = f2bf(k2 * c2 + k1 * s2);
    }
  }
  // v normalize + transpose into vo[d][r]
#pragma unroll
  for (int u = 0; u < 9; u++) {
    int d = p * 9 + u;
    vo[d * 48 + r] = f2bf(bf2f(in_t[r * 224 + 144 + d]) * rv);
  }
  // zero pads: qo/ko cols 72..127 (granules 9..15)
  if (p < 7) {
    uint4 z = make_uint4(0, 0, 0, 0);
    *(uint4*)&qo[r * 128 + (9 + p) * 8] = z;
    *(uint4*)&ko[r * 128 + (9 + p) * 8] = z;
  }
  // zero pads: vo rows 72..79 (cols 0..31)
  if (tid < 32) {
    int d = 72 + (tid >> 2), g = tid & 3;
    *(uint4*)&vo[d * 48 + g * 8] = make_uint4(0, 0, 0, 0);
  }
  __syncthreads();

  // phase 3: coalesced stores
#pragma unroll
  for (int k = 0; k < 2; k++) {
    int g = tid + k * 256;  // 512 granules
    int row = g >> 4, j = g & 15;
    *(uint4*)(Qp + ((size_t)h * SEQ + n0 + row) * 128 + j * 8) = *(const uint4*)&qo[row * 128 + j * 8];
    *(uint4*)(Kp + ((size_t)h * SEQ + n0 + row) * 128 + j * 8) = *(const uint4*)&ko[row * 128 + j * 8];
  }
#pragma unroll
  for (int k = 0; k < 2; k++) {
    int g = tid + k * 256;
    if (g < 320) {
      int d = g >> 2, j = g & 3;
      *(uint4*)(Vt + ((size_t)h * 80 + d) * SEQ + n0 + j * 8) = *(const uint4*)&vo[d * 48 + j * 8];
    }
  }
}

// ---------------- flash attention (swapped-QK^T, dbuf, 1 barrier/tile) ----------------
// grid (32 q-tiles of 128, 16 heads), 4 waves x 32 q-rows each, 64-key tiles
__global__ __launch_bounds__(256, 2) void attn(const u16* __restrict__ Qp,
                                               const u16* __restrict__ Kp,
                                               const u16* __restrict__ Vt,
                                               u16* __restrict__ AO) {
  __shared__ __align__(16) u16 Ks[2][64 * 128];  // 32 KB
  __shared__ __align__(16) u16 Vs[2][80 * 64];   // 20 KB
  __shared__ __align__(16) u16 Ps[4][32 * 64];   // 16 KB (per-wave P)
  const int tid = threadIdx.x;
  const int wave = tid >> 6, lane = tid & 63;
  const int l15 = lane & 15, l4 = lane >> 4;
  const int h = blockIdx.y;
  const int q0 = blockIdx.x * 128 + wave * 32;

  // Q fragments (B-operand: col = l15 -> q, k-slice = kk*32 + l4*8)
  bf16x8 bq[2][3];
#pragma unroll
  for (int qf = 0; qf < 2; qf++) {
    const u16* qbase = Qp + ((size_t)h * SEQ + q0 + qf * 16 + l15) * 128;
#pragma unroll
    for (int kk = 0; kk < 3; kk++) bq[qf][kk] = *(const bf16x8*)(qbase + kk * 32 + l4 * 8);
  }

  f32x4 acc[2][5] = {};
  float mi_[2] = {-1e30f, -1e30f};
  float li_[2] = {0.0f, 0.0f};

  auto stage = [&](int buf, int k0) {
    // K: 64 rows x 16 granules, source-swizzled, linear LDS
#pragma unroll
    for (int rr = 0; rr < 4; rr++) {
      int g = (rr << 8) + tid;
      int m = g >> 4, j = g & 15;
      int js = j ^ (m & 15);
      gload_lds16(Kp + ((size_t)h * SEQ + k0 + m) * 128 + js * 8,
                  (void*)&Ks[buf][(size_t)((rr << 8) + (wave << 6)) * 8]);
    }
    // V: 80 rows x 8 granules
#pragma unroll
    for (int rr = 0; rr < 3; rr++) {
      int c = (rr << 2) + wave;
      if (c < 10) {
        int g = (c << 6) + lane;
        int d = g >> 3, j = g & 7;
        int js = j ^ (d & 7);
        gload_lds16(Vt + ((size_t)h * 80 + d) * SEQ + k0 + js * 8,
                    (void*)&Vs[buf][(size_t)(c << 6) * 8]);
      }
    }
  };

  stage(0, 0);
  for (int t = 0; t < 64; t++) {
    __syncthreads();  // drains vmcnt: tile t staged; all waves done with buf t+1's old data
    if (t < 63) stage((t + 1) & 1, (t + 1) * 64);
    const u16* Kb = Ks[t & 1];
    const u16* Vb = Vs[t & 1];

    // S^T = K * Q  (col = q = l15, row = k = l4*4 + r + 16*nf)
    f32x4 s[2][4] = {};
#pragma unroll
    for (int kk = 0; kk < 3; kk++) {
      int slot = (kk << 2) + l4;
      bf16x8 ak[4];
#pragma unroll
      for (int nf = 0; nf < 4; nf++) {
        int row = (nf << 4) + l15;
        ak[nf] = *(const bf16x8*)&Kb[row * 128 + ((slot ^ (row & 15)) << 3)];
      }
#pragma unroll
      for (int qf = 0; qf < 2; qf++)
#pragma unroll
        for (int nf = 0; nf < 4; nf++)
          s[qf][nf] = __builtin_amdgcn_mfma_f32_16x16x32_bf16(ak[nf], bq[qf][kk], s[qf][nf], 0, 0, 0);
    }

    // online softmax: each lane owns 16 k-scores of q-column (q0 + qf*16 + l15)
    float scl[2];
#pragma unroll
    for (int qf = 0; qf < 2; qf++) {
      float v0 = fmaxf(fmaxf(s[qf][0][0], s[qf][0][1]), fmaxf(s[qf][0][2], s[qf][0][3]));
      float v1 = fmaxf(fmaxf(s[qf][1][0], s[qf][1][1]), fmaxf(s[qf][1][2], s[qf][1][3]));
      float v2 = fmaxf(fmaxf(s[qf][2][0], s[qf][2][1]), fmaxf(s[qf][2][2], s[qf][2][3]));
      float v3 = fmaxf(fmaxf(s[qf][3][0], s[qf][3][1]), fmaxf(s[qf][3][2], s[qf][3][3]));
      float v = fmaxf(fmaxf(v0, v1), fmaxf(v2, v3));
      v = fmaxf(v, __shfl_xor(v, 16));
      v = fmaxf(v, __shfl_xor(v, 32));
      float mnew = fmaxf(mi_[qf], v);
      scl[qf] = __expf(mi_[qf] - mnew);
      mi_[qf] = mnew;
      float rsum = 0.0f;
      int row = (qf << 4) + l15;
#pragma unroll
      for (int nf = 0; nf < 4; nf++) {
        ushort4 pk;
        float p0 = __expf(s[qf][nf][0] - mnew);
        float p1 = __expf(s[qf][nf][1] - mnew);
        float p2 = __expf(s[qf][nf][2] - mnew);
        float p3 = __expf(s[qf][nf][3] - mnew);
        rsum += (p0 + p1) + (p2 + p3);
        pk.x = f2bf(p0); pk.y = f2bf(p1); pk.z = f2bf(p2); pk.w = f2bf(p3);
        int gg = (nf << 2) + l4;
        int gs = gg ^ ((row & 7) << 1);
        *(ushort4*)&Ps[wave][row * 64 + gs * 4] = pk;
      }
      rsum += __shfl_xor(rsum, 16);
      rsum += __shfl_xor(rsum, 32);
      li_[qf] = li_[qf] * scl[qf] + rsum;
    }

    // rescale accumulator (scl lives at lane l15 == q-row; redistribute)
#pragma unroll
    for (int qf = 0; qf < 2; qf++)
#pragma unroll
      for (int r = 0; r < 4; r++) {
        float sr = __shfl(scl[qf], (l4 << 2) + r);
#pragma unroll
        for (int ni = 0; ni < 5; ni++) acc[qf][ni][r] *= sr;
      }

    // PV: O[q][d] += P[q][k] * V[k][d]
#pragma unroll
    for (int kk = 0; kk < 2; kk++) {
      bf16x8 pa[2];
#pragma unroll
      for (int qf = 0; qf < 2; qf++) {
        int row = (qf << 4) + l15;
        int gb = ((kk << 3) + (l4 << 1)) ^ ((row & 7) << 1);
        pa[qf] = *(const bf16x8*)&Ps[wave][row * 64 + gb * 4];
      }
      int slot = (kk << 2) + l4;
#pragma unroll
      for (int ni = 0; ni < 5; ni++) {
        int d = (ni << 4) + l15;
        bf16x8 bv = *(const bf16x8*)&Vb[d * 64 + ((slot ^ (d & 7)) << 3)];
#pragma unroll
        for (int qf = 0; qf < 2; qf++)
          acc[qf][ni] = __builtin_amdgcn_mfma_f32_16x16x32_bf16(pa[qf], bv, acc[qf][ni], 0, 0, 0);
      }
    }
  }

  // epilogue
#pragma unroll
  for (int qf = 0; qf < 2; qf++)
#pragma unroll
    for (int r = 0; r < 4; r++) {
      float inv = 1.0f / __shfl(li_[qf], (l4 << 2) + r);
      int q = q0 + (qf << 4) + (l4 << 2) + r;
#pragma unroll
      for (int ni = 0; ni < 5; ni++) {
        int d = (ni << 4) + l15;
        if (d < HD) AO[(size_t)q * HID + h * HD + d] = f2bf(acc[qf][ni][r] * inv);
      }
    }
}

extern "C" void kernel_launch(void* const* d_in, const int* in_sizes, int n_in,
                              void* d_out, int out_size, void* d_ws, size_t ws_size,
                              hipStream_t stream) {
  const float* X = (const float*)d_in[0];
  const float* cosv = (const float*)d_in[1];
  const float* sinv = (const float*)d_in[2];
  const float* Wq = (const float*)d_in[3];
  const float* Wk = (const float*)d_in[4];
  const float* Wv = (const float*)d_in[5];
  const float* Wo = (const float*)d_in[6];
  const float* qsc = (const float*)d_in[7];
  const float* ksc = (const float*)d_in[8];
  float* out = (float*)d_out;

  uint8_t* ws = (uint8_t*)d_ws;
  u16* Xb  = (u16*)(ws);                 //  9,437,184 B  (4096x1152 bf16)
  u16* Wt  = (u16*)(ws + 9437184);       //  7,962,624 B  (3456x1152 bf16)
  u16* Wot = (u16*)(ws + 17399808);      //  2,654,208 B  (1152x1152 bf16)
  u16* C1  = (u16*)(ws + 20054016);      // 28,311,552 B  (4096x3456 bf16)
  u16* Qp  = (u16*)(ws + 48365568);      // 16,777,216 B  (16x4096x128 bf16)
  u16* Kp  = (u16*)(ws + 65142784);      // 16,777,216 B
  u16* Vt  = (u16*)(ws + 81920000);      // 10,485,760 B  (16x80x4096 bf16)
  u16* AO  = Xb;                         // reuse: Xb consumed by GEMM1 before attn writes

  cvt_x<<<4608, 256, 0, stream>>>(X, Xb, (SEQ * HID) / 4);
  transpose_w<<<dim3(36, 36, 4), 256, 0, stream>>>(Wq, Wk, Wv, Wo, Wt, Wot);
  gemm_bt<1><<<dim3(32, 27), 256, 0, stream>>>(Xb, Wt, (void*)C1, SEQ, 3456, HID);
  norm_rope<<<dim3(128, 16), 256, 0, stream>>>(C1, cosv, sinv, qsc, ksc, Qp, Kp, Vt);
  attn<<<dim3(32, 16), 256, 0, stream>>>(Qp, Kp, Vt, AO);
  gemm_bt<0><<<dim3(32, 9), 256, 0, stream>>>(AO, Wot, (void*)out, SEQ, HID, HID);
}

// Round 5
// 307.625 us; speedup vs baseline: 1.5252x; 1.1175x over previous
//
#include <hip/hip_runtime.h>
#include <stdint.h>

typedef unsigned short u16;
typedef __bf16 bf16x8 __attribute__((ext_vector_type(8)));
typedef float f32x4 __attribute__((ext_vector_type(4)));
typedef __attribute__((address_space(1))) const unsigned int as1_u32;
typedef __attribute__((address_space(3))) unsigned int as3_u32;

#define SEQ 4096
#define HID 1152
#define NH 16
#define HD 72

__device__ __forceinline__ void gload_lds16(const void* g, void* l) {
  __builtin_amdgcn_global_load_lds((as1_u32*)g, (as3_u32*)l, 16, 0, 0);
}
__device__ __forceinline__ u16 f2bf(float f) {
  __bf16 h = (__bf16)f;
  return __builtin_bit_cast(u16, h);
}
__device__ __forceinline__ float bf2f(u16 u) {
  unsigned int x = ((unsigned int)u) << 16;
  return __builtin_bit_cast(float, x);
}

// ---------------- cast X fp32 -> bf16 ----------------
__global__ void cvt_x(const float* __restrict__ X, u16* __restrict__ Xb, int n4) {
  int i = blockIdx.x * blockDim.x + threadIdx.x;
  if (i < n4) {
    float4 v = *(const float4*)(X + (size_t)i * 4);
    unsigned int lo = f2bf(v.x) | ((unsigned int)f2bf(v.y) << 16);
    unsigned int hi = f2bf(v.z) | ((unsigned int)f2bf(v.w) << 16);
    *(uint2*)(Xb + (size_t)i * 4) = make_uint2(lo, hi);
  }
}

// ---------------- transpose + cast W (1152x1152 each) ----------------
__global__ void transpose_w(const float* __restrict__ Wq, const float* __restrict__ Wk,
                            const float* __restrict__ Wv, const float* __restrict__ Wo,
                            u16* __restrict__ Wt, u16* __restrict__ Wot) {
  __shared__ __align__(16) float t[32][33];
  int z = blockIdx.z;
  const float* src = (z == 0) ? Wq : (z == 1) ? Wk : (z == 2) ? Wv : Wo;
  u16* dst = (z < 3) ? (Wt + (size_t)z * HID * HID) : Wot;
  int tx = threadIdx.x & 31, ty = threadIdx.x >> 5;  // 32 x 8
  int c0 = blockIdx.x * 32, r0 = blockIdx.y * 32;
#pragma unroll
  for (int i = 0; i < 4; i++)
    t[ty + i * 8][tx] = src[(size_t)(r0 + ty + i * 8) * HID + c0 + tx];
  __syncthreads();
#pragma unroll
  for (int i = 0; i < 4; i++)
    dst[(size_t)(c0 + ty + i * 8) * HID + r0 + tx] = f2bf(t[tx][ty + i * 8]);
}

// ---------------- bf16 GEMM  C[M][N] = A[M][K] * Bt[N][K]^T ----------------
template <int OUTBF16>
__global__ __launch_bounds__(256, 2) void gemm_bt(const u16* __restrict__ A,
                                                  const u16* __restrict__ Bt,
                                                  void* __restrict__ Cout,
                                                  int M, int N, int K) {
  __shared__ __align__(16) u16 lds[2][2][128 * 64];
  const int tid = threadIdx.x;
  const int wave = tid >> 6, lane = tid & 63;
  const int l15 = lane & 15, l4 = lane >> 4;
  const size_t bm = (size_t)blockIdx.x * 128, bn = (size_t)blockIdx.y * 128;
  const int wm = (wave >> 1) * 64, wn = (wave & 1) * 64;
  const int nt = K >> 6;

  f32x4 acc[4][4] = {};

  auto stage = [&](int buf, int kt) {
    const int k0 = kt << 6;
#pragma unroll
    for (int r = 0; r < 4; r++) {
      int idx = (r << 8) + tid;
      int m = idx >> 3, j = idx & 7;
      int js = j ^ (m & 7);
      void* ldsA = (void*)&lds[buf][0][(size_t)((r << 8) + (wave << 6)) * 8];
      void* ldsB = (void*)&lds[buf][1][(size_t)((r << 8) + (wave << 6)) * 8];
      gload_lds16(A + (bm + m) * (size_t)K + k0 + js * 8, ldsA);
      gload_lds16(Bt + (bn + m) * (size_t)K + k0 + js * 8, ldsB);
    }
  };

  stage(0, 0);
  for (int t = 0; t < nt; t++) {
    __syncthreads();
    if (t + 1 < nt) stage((t + 1) & 1, t + 1);
    const u16* As = &lds[t & 1][0][0];
    const u16* Bs = &lds[t & 1][1][0];
#pragma unroll
    for (int kk = 0; kk < 2; kk++) {
      bf16x8 af[4], bfr[4];
      int slot = (kk << 2) + l4;
#pragma unroll
      for (int mi = 0; mi < 4; mi++) {
        int m = wm + (mi << 4) + l15;
        af[mi] = *(const bf16x8*)&As[m * 64 + ((slot ^ (m & 7)) << 3)];
      }
#pragma unroll
      for (int ni = 0; ni < 4; ni++) {
        int n = wn + (ni << 4) + l15;
        bfr[ni] = *(const bf16x8*)&Bs[n * 64 + ((slot ^ (n & 7)) << 3)];
      }
#pragma unroll
      for (int mi = 0; mi < 4; mi++)
#pragma unroll
        for (int ni = 0; ni < 4; ni++)
          acc[mi][ni] = __builtin_amdgcn_mfma_f32_16x16x32_bf16(af[mi], bfr[ni], acc[mi][ni], 0, 0, 0);
    }
  }

#pragma unroll
  for (int mi = 0; mi < 4; mi++)
#pragma unroll
    for (int ni = 0; ni < 4; ni++)
#pragma unroll
      for (int r = 0; r < 4; r++) {
        size_t m = bm + wm + (mi << 4) + (l4 << 2) + r;
        size_t n = bn + wn + (ni << 4) + l15;
        if (OUTBF16)
          ((u16*)Cout)[m * N + n] = f2bf(acc[mi][ni][r]);
        else
          ((float*)Cout)[m * N + n] = acc[mi][ni][r];
      }
}

// ---------------- fused RMSNorm + 2D RoPE (tiled, coalesced) ----------------
// C1 bf16 [4096][3456] -> Qp,Kp bf16 [h][n][96] (pad 72..95 = 0),
//                         Vt bf16 [h][80][4096] (pad rows 72..79 = 0)
__global__ __launch_bounds__(256, 2) void norm_rope(
    const u16* __restrict__ C1, const float* __restrict__ cosv,
    const float* __restrict__ sinv, const float* __restrict__ qsc,
    const float* __restrict__ ksc, u16* __restrict__ Qp, u16* __restrict__ Kp,
    u16* __restrict__ Vt) {
  __shared__ __align__(16) u16 in_t[32 * 224];
  __shared__ __align__(16) u16 qo[32 * 96];
  __shared__ __align__(16) u16 ko[32 * 96];
  __shared__ __align__(16) u16 vo[80 * 48];
  const int tid = threadIdx.x;
  const int h = blockIdx.y;
  const int n0 = blockIdx.x * 32;

  // phase 1: cooperative load of the 32x216 tile (16B granules)
#pragma unroll
  for (int k = 0; k < 4; k++) {
    int g = tid + k * 256;
    if (g < 864) {
      int row = g / 27, j = g - row * 27;
      int seg = j / 9, c = (j - seg * 9) * 8;
      const u16* src = C1 + (size_t)(n0 + row) * 3456 + seg * 1152 + h * HD + c;
      *(uint4*)&in_t[row * 224 + j * 8] = *(const uint4*)src;
    }
  }
  __syncthreads();

  // phase 2: per-row (8 lanes/row) rms + rope + v-transpose
  const int r = tid >> 3, p = tid & 7;
  float sq = 0, sk = 0, sv = 0;
  auto acc8 = [&](int off, float& s) {
    uint4 v = *(const uint4*)&in_t[r * 224 + off];
    unsigned int vv[4] = {v.x, v.y, v.z, v.w};
#pragma unroll
    for (int q = 0; q < 4; q++) {
      float a = bf2f((u16)(vv[q] & 0xffff));
      float b = bf2f((u16)(vv[q] >> 16));
      s += a * a + b * b;
    }
  };
  acc8(0 + p * 8, sq);
  acc8(72 + p * 8, sk);
  acc8(144 + p * 8, sv);
  if (p == 0) { acc8(64, sq); acc8(136, sk); acc8(208, sv); }
#pragma unroll
  for (int m = 1; m < 8; m <<= 1) {
    sq += __shfl_xor(sq, m);
    sk += __shfl_xor(sk, m);
    sv += __shfl_xor(sv, m);
  }
  const float rq = rsqrtf(sq * (1.0f / 72.0f) + 1e-6f);
  const float rk = rsqrtf(sk * (1.0f / 72.0f) + 1e-6f);
  const float rv = rsqrtf(sv * (1.0f / 72.0f) + 1e-6f);

#pragma unroll
  for (int u = 0; u < 5; u++) {
    int ti = p + (u << 3);
    if (ti < 36) {
      int i1 = ti + ((ti >= 18) ? 18 : 0);
      int i2 = i1 + 18;
      const float* cb = cosv + (size_t)(n0 + r) * HD;
      const float* sb = sinv + (size_t)(n0 + r) * HD;
      float c1 = cb[i1], c2 = cb[i2], s1 = sb[i1], s2 = sb[i2];
      float q1 = bf2f(in_t[r * 224 + i1]) * rq * qsc[i1];
      float q2 = bf2f(in_t[r * 224 + i2]) * rq * qsc[i2];
      float k1 = bf2f(in_t[r * 224 + 72 + i1]) * rk * ksc[i1];
      float k2 = bf2f(in_t[r * 224 + 72 + i2]) * rk * ksc[i2];
      qo[r * 96 + i1] = f2bf(q1 * c1 - q2 * s1);
      qo[r * 96 + i2] = f2bf(q2 * c2 + q1 * s2);
      ko[r * 96 + i1] = f2bf(k1 * c1 - k2 * s1);
      ko[r * 96 + i2] = f2bf(k2 * c2 + k1 * s2);
    }
  }
#pragma unroll
  for (int u = 0; u < 9; u++) {
    int d = p * 9 + u;
    vo[d * 48 + r] = f2bf(bf2f(in_t[r * 224 + 144 + d]) * rv);
  }
  // zero pads: qo/ko granules 9..11 (cols 72..95)
  if (p < 3) {
    uint4 z = make_uint4(0, 0, 0, 0);
    *(uint4*)&qo[r * 96 + (9 + p) * 8] = z;
    *(uint4*)&ko[r * 96 + (9 + p) * 8] = z;
  }
  // zero pads: vo rows 72..79
  if (tid < 32) {
    int d = 72 + (tid >> 2), g = tid & 3;
    *(uint4*)&vo[d * 48 + g * 8] = make_uint4(0, 0, 0, 0);
  }
  __syncthreads();

  // phase 3: coalesced stores (32 rows x 12 granules = 384)
#pragma unroll
  for (int k = 0; k < 2; k++) {
    int g = tid + k * 256;
    if (g < 384) {
      int row = g / 12, j = g - row * 12;
      *(uint4*)(Qp + ((size_t)h * SEQ + n0 + row) * 96 + j * 8) = *(const uint4*)&qo[row * 96 + j * 8];
      *(uint4*)(Kp + ((size_t)h * SEQ + n0 + row) * 96 + j * 8) = *(const uint4*)&ko[row * 96 + j * 8];
    }
  }
#pragma unroll
  for (int k = 0; k < 2; k++) {
    int g = tid + k * 256;
    if (g < 320) {
      int d = g >> 2, j = g & 3;
      *(uint4*)(Vt + ((size_t)h * 80 + d) * SEQ + n0 + j * 8) = *(const uint4*)&vo[d * 48 + j * 8];
    }
  }
}

// ---------------- flash attention ----------------
// 512 threads = 8 waves x 16 q-rows (QBLK=128), 64-key tiles, dbuf, 1 barrier/tile.
// Q/K stored [h][n][96]; V stored [h][80][n]. Head->XCD clustered block remap.
__global__ __launch_bounds__(512, 4) void attn(const u16* __restrict__ Qp,
                                               const u16* __restrict__ Kp,
                                               const u16* __restrict__ Vt,
                                               u16* __restrict__ AO) {
  __shared__ __align__(16) u16 Ks[2][64 * 96];   // 24 KB
  __shared__ __align__(16) u16 Vs[2][80 * 64];   // 20 KB
  __shared__ __align__(16) u16 Ps[8][16 * 64];   // 16 KB (per-wave P)
  const int tid = threadIdx.x;
  const int wave = tid >> 6, lane = tid & 63;
  const int l15 = lane & 15, l4 = lane >> 4;

  // head->XCD clustering: XCD = linear_bid % 8; put each head entirely on one XCD
  const int bid = blockIdx.x + (blockIdx.y << 5);
  const int h = ((bid & 7) << 1) | ((bid >> 3) & 1);
  const int qt = bid >> 4;  // 0..31
  const int q0 = qt * 128 + wave * 16;

  // Q fragment (B-operand: col q = l15, k-slice = kk*32 + l4*8)
  bf16x8 bq[3];
  const u16* qbase = Qp + ((size_t)h * SEQ + q0 + l15) * 96;
#pragma unroll
  for (int kk = 0; kk < 3; kk++) bq[kk] = *(const bf16x8*)(qbase + kk * 32 + l4 * 8);

  f32x4 acc[5] = {};
  float mi_ = -1e30f, li_ = 0.0f;

  auto stage = [&](int buf, int k0) {
    // K: 64 rows x 12 granules = 768, fully linear (no swizzle needed: 192B stride)
    {
      int g = tid;
      int m = g / 12, j = g - m * 12;
      gload_lds16(Kp + ((size_t)h * SEQ + k0 + m) * 96 + j * 8,
                  (void*)&Ks[buf][(size_t)(wave << 6) * 8]);
      if (wave < 4) {
        int g2 = tid + 512;
        int m2 = g2 / 12, j2 = g2 - m2 * 12;
        gload_lds16(Kp + ((size_t)h * SEQ + k0 + m2) * 96 + j2 * 8,
                    (void*)&Ks[buf][(size_t)(512 + (wave << 6)) * 8]);
      }
    }
    // V: 80 rows x 8 granules = 640, source-swizzled
    {
      int d = tid >> 3, j = tid & 7;
      int js = j ^ (d & 7);
      gload_lds16(Vt + ((size_t)h * 80 + d) * SEQ + k0 + js * 8,
                  (void*)&Vs[buf][(size_t)(wave << 6) * 8]);
      if (wave < 2) {
        int g2 = tid + 512;
        int d2 = g2 >> 3, j2 = g2 & 7;
        int js2 = j2 ^ (d2 & 7);
        gload_lds16(Vt + ((size_t)h * 80 + d2) * SEQ + k0 + js2 * 8,
                    (void*)&Vs[buf][(size_t)(512 + (wave << 6)) * 8]);
      }
    }
  };

  stage(0, 0);
  for (int t = 0; t < 64; t++) {
    __syncthreads();  // tile t staged (vmcnt drained); buf t+1 free
    if (t < 63) stage((t + 1) & 1, (t + 1) * 64);
    const u16* Kb = Ks[t & 1];
    const u16* Vb = Vs[t & 1];

    // S^T = K * Q  (col q = l15, row k = nf*16 + l4*4 + r)
    f32x4 s[4] = {};
    __builtin_amdgcn_s_setprio(1);
#pragma unroll
    for (int kk = 0; kk < 3; kk++) {
      int slot = (kk << 2) + l4;
      bf16x8 ak[4];
#pragma unroll
      for (int nf = 0; nf < 4; nf++) {
        int row = (nf << 4) + l15;
        ak[nf] = *(const bf16x8*)&Kb[row * 96 + slot * 8];
      }
#pragma unroll
      for (int nf = 0; nf < 4; nf++)
        s[nf] = __builtin_amdgcn_mfma_f32_16x16x32_bf16(ak[nf], bq[kk], s[nf], 0, 0, 0);
    }
    __builtin_amdgcn_s_setprio(0);

    // online softmax: lane owns 16 k-scores of q-column l15
    float v0 = fmaxf(fmaxf(s[0][0], s[0][1]), fmaxf(s[0][2], s[0][3]));
    float v1 = fmaxf(fmaxf(s[1][0], s[1][1]), fmaxf(s[1][2], s[1][3]));
    float v2 = fmaxf(fmaxf(s[2][0], s[2][1]), fmaxf(s[2][2], s[2][3]));
    float v3 = fmaxf(fmaxf(s[3][0], s[3][1]), fmaxf(s[3][2], s[3][3]));
    float v = fmaxf(fmaxf(v0, v1), fmaxf(v2, v3));
    v = fmaxf(v, __shfl_xor(v, 16));
    v = fmaxf(v, __shfl_xor(v, 32));
    float mnew = fmaxf(mi_, v);
    float scl = __expf(mi_ - mnew);
    mi_ = mnew;
    float rsum = 0.0f;
#pragma unroll
    for (int nf = 0; nf < 4; nf++) {
      ushort4 pk;
      float p0 = __expf(s[nf][0] - mnew);
      float p1 = __expf(s[nf][1] - mnew);
      float p2 = __expf(s[nf][2] - mnew);
      float p3 = __expf(s[nf][3] - mnew);
      rsum += (p0 + p1) + (p2 + p3);
      pk.x = f2bf(p0); pk.y = f2bf(p1); pk.z = f2bf(p2); pk.w = f2bf(p3);
      int gs = ((nf << 2) + l4) ^ ((l15 & 7) << 1);
      *(ushort4*)&Ps[wave][l15 * 64 + gs * 4] = pk;
    }
    li_ = li_ * scl + rsum;  // lane-partial sum; reduced in epilogue

    // rescale accumulator (acc row q = l4*4+r; scl lives at lane l15==q)
#pragma unroll
    for (int r = 0; r < 4; r++) {
      float sr = __shfl(scl, (l4 << 2) + r);
#pragma unroll
      for (int ni = 0; ni < 5; ni++) acc[ni][r] *= sr;
    }

    // PV: O[q][d] += P[q][k] * V[k][d]
    __builtin_amdgcn_s_setprio(1);
#pragma unroll
    for (int kk = 0; kk < 2; kk++) {
      int gb = ((kk << 3) + (l4 << 1)) ^ ((l15 & 7) << 1);
      bf16x8 pa = *(const bf16x8*)&Ps[wave][l15 * 64 + gb * 4];
      int slot = (kk << 2) + l4;
#pragma unroll
      for (int ni = 0; ni < 5; ni++) {
        int d = (ni << 4) + l15;
        bf16x8 bv = *(const bf16x8*)&Vb[d * 64 + ((slot ^ (d & 7)) << 3)];
        acc[ni] = __builtin_amdgcn_mfma_f32_16x16x32_bf16(pa, bv, acc[ni], 0, 0, 0);
      }
    }
    __builtin_amdgcn_s_setprio(0);
  }

  // epilogue: finish row-sum reduce, normalize, store
  li_ += __shfl_xor(li_, 16);
  li_ += __shfl_xor(li_, 32);
#pragma unroll
  for (int r = 0; r < 4; r++) {
    float inv = 1.0f / __shfl(li_, (l4 << 2) + r);
    int q = q0 + (l4 << 2) + r;
#pragma unroll
    for (int ni = 0; ni < 5; ni++) {
      int d = (ni << 4) + l15;
      if (d < HD) AO[(size_t)q * HID + h * HD + d] = f2bf(acc[ni][r] * inv);
    }
  }
}

extern "C" void kernel_launch(void* const* d_in, const int* in_sizes, int n_in,
                              void* d_out, int out_size, void* d_ws, size_t ws_size,
                              hipStream_t stream) {
  const float* X = (const float*)d_in[0];
  const float* cosv = (const float*)d_in[1];
  const float* sinv = (const float*)d_in[2];
  const float* Wq = (const float*)d_in[3];
  const float* Wk = (const float*)d_in[4];
  const float* Wv = (const float*)d_in[5];
  const float* Wo = (const float*)d_in[6];
  const float* qsc = (const float*)d_in[7];
  const float* ksc = (const float*)d_in[8];
  float* out = (float*)d_out;

  uint8_t* ws = (uint8_t*)d_ws;
  u16* Xb  = (u16*)(ws);                 //  9,437,184 B  (4096x1152 bf16)
  u16* Wt  = (u16*)(ws + 9437184);       //  7,962,624 B  (3456x1152 bf16)
  u16* Wot = (u16*)(ws + 17399808);      //  2,654,208 B  (1152x1152 bf16)
  u16* C1  = (u16*)(ws + 20054016);      // 28,311,552 B  (4096x3456 bf16)
  u16* Qp  = (u16*)(ws + 48365568);      // 12,582,912 B  (16x4096x96 bf16)
  u16* Kp  = (u16*)(ws + 60948480);      // 12,582,912 B
  u16* Vt  = (u16*)(ws + 73531392);      // 10,485,760 B  (16x80x4096 bf16)
  u16* AO  = Xb;                         // reuse: Xb consumed by GEMM1 before attn writes

  cvt_x<<<4608, 256, 0, stream>>>(X, Xb, (SEQ * HID) / 4);
  transpose_w<<<dim3(36, 36, 4), 256, 0, stream>>>(Wq, Wk, Wv, Wo, Wt, Wot);
  gemm_bt<1><<<dim3(32, 27), 256, 0, stream>>>(Xb, Wt, (void*)C1, SEQ, 3456, HID);
  norm_rope<<<dim3(128, 16), 256, 0, stream>>>(C1, cosv, sinv, qsc, ksc, Qp, Kp, Vt);
  attn<<<dim3(32, 16), 512, 0, stream>>>(Qp, Kp, Vt, AO);
  gemm_bt<0><<<dim3(32, 9), 256, 0, stream>>>(AO, Wot, (void*)out, SEQ, HID, HID);
}

// Round 6
// 299.519 us; speedup vs baseline: 1.5665x; 1.0271x over previous
//
#include <hip/hip_runtime.h>
#include <stdint.h>

typedef unsigned short u16;
typedef __bf16 bf16x8 __attribute__((ext_vector_type(8)));
typedef float f32x4 __attribute__((ext_vector_type(4)));
typedef __attribute__((address_space(1))) const unsigned int as1_u32;
typedef __attribute__((address_space(3))) unsigned int as3_u32;

#define SEQ 4096
#define HID 1152
#define NH 16
#define HD 72

__device__ __forceinline__ void gload_lds16(const void* g, void* l) {
  __builtin_amdgcn_global_load_lds((as1_u32*)g, (as3_u32*)l, 16, 0, 0);
}
__device__ __forceinline__ u16 f2bf(float f) {
  __bf16 h = (__bf16)f;
  return __builtin_bit_cast(u16, h);
}
__device__ __forceinline__ float bf2f(u16 u) {
  unsigned int x = ((unsigned int)u) << 16;
  return __builtin_bit_cast(float, x);
}

// ---------------- cast X fp32 -> bf16 ----------------
__global__ void cvt_x(const float* __restrict__ X, u16* __restrict__ Xb, int n4) {
  int i = blockIdx.x * blockDim.x + threadIdx.x;
  if (i < n4) {
    float4 v = *(const float4*)(X + (size_t)i * 4);
    unsigned int lo = f2bf(v.x) | ((unsigned int)f2bf(v.y) << 16);
    unsigned int hi = f2bf(v.z) | ((unsigned int)f2bf(v.w) << 16);
    *(uint2*)(Xb + (size_t)i * 4) = make_uint2(lo, hi);
  }
}

// ---------------- transpose + cast W (1152x1152 each) ----------------
__global__ void transpose_w(const float* __restrict__ Wq, const float* __restrict__ Wk,
                            const float* __restrict__ Wv, const float* __restrict__ Wo,
                            u16* __restrict__ Wt, u16* __restrict__ Wot) {
  __shared__ __align__(16) float t[32][33];
  int z = blockIdx.z;
  const float* src = (z == 0) ? Wq : (z == 1) ? Wk : (z == 2) ? Wv : Wo;
  u16* dst = (z < 3) ? (Wt + (size_t)z * HID * HID) : Wot;
  int tx = threadIdx.x & 31, ty = threadIdx.x >> 5;  // 32 x 8
  int c0 = blockIdx.x * 32, r0 = blockIdx.y * 32;
#pragma unroll
  for (int i = 0; i < 4; i++)
    t[ty + i * 8][tx] = src[(size_t)(r0 + ty + i * 8) * HID + c0 + tx];
  __syncthreads();
#pragma unroll
  for (int i = 0; i < 4; i++)
    dst[(size_t)(c0 + ty + i * 8) * HID + r0 + tx] = f2bf(t[tx][ty + i * 8]);
}

// ---------------- bf16 GEMM  C[M][N] = A[M][K] * Bt[N][K]^T ----------------
template <int OUTBF16>
__global__ __launch_bounds__(256, 2) void gemm_bt(const u16* __restrict__ A,
                                                  const u16* __restrict__ Bt,
                                                  void* __restrict__ Cout,
                                                  int M, int N, int K) {
  __shared__ __align__(16) u16 lds[2][2][128 * 64];
  const int tid = threadIdx.x;
  const int wave = tid >> 6, lane = tid & 63;
  const int l15 = lane & 15, l4 = lane >> 4;
  const size_t bm = (size_t)blockIdx.x * 128, bn = (size_t)blockIdx.y * 128;
  const int wm = (wave >> 1) * 64, wn = (wave & 1) * 64;
  const int nt = K >> 6;

  f32x4 acc[4][4] = {};

  auto stage = [&](int buf, int kt) {
    const int k0 = kt << 6;
#pragma unroll
    for (int r = 0; r < 4; r++) {
      int idx = (r << 8) + tid;
      int m = idx >> 3, j = idx & 7;
      int js = j ^ (m & 7);
      void* ldsA = (void*)&lds[buf][0][(size_t)((r << 8) + (wave << 6)) * 8];
      void* ldsB = (void*)&lds[buf][1][(size_t)((r << 8) + (wave << 6)) * 8];
      gload_lds16(A + (bm + m) * (size_t)K + k0 + js * 8, ldsA);
      gload_lds16(Bt + (bn + m) * (size_t)K + k0 + js * 8, ldsB);
    }
  };

  stage(0, 0);
  for (int t = 0; t < nt; t++) {
    __syncthreads();
    if (t + 1 < nt) stage((t + 1) & 1, t + 1);
    const u16* As = &lds[t & 1][0][0];
    const u16* Bs = &lds[t & 1][1][0];
#pragma unroll
    for (int kk = 0; kk < 2; kk++) {
      bf16x8 af[4], bfr[4];
      int slot = (kk << 2) + l4;
#pragma unroll
      for (int mi = 0; mi < 4; mi++) {
        int m = wm + (mi << 4) + l15;
        af[mi] = *(const bf16x8*)&As[m * 64 + ((slot ^ (m & 7)) << 3)];
      }
#pragma unroll
      for (int ni = 0; ni < 4; ni++) {
        int n = wn + (ni << 4) + l15;
        bfr[ni] = *(const bf16x8*)&Bs[n * 64 + ((slot ^ (n & 7)) << 3)];
      }
#pragma unroll
      for (int mi = 0; mi < 4; mi++)
#pragma unroll
        for (int ni = 0; ni < 4; ni++)
          acc[mi][ni] = __builtin_amdgcn_mfma_f32_16x16x32_bf16(af[mi], bfr[ni], acc[mi][ni], 0, 0, 0);
    }
  }

#pragma unroll
  for (int mi = 0; mi < 4; mi++)
#pragma unroll
    for (int ni = 0; ni < 4; ni++)
#pragma unroll
      for (int r = 0; r < 4; r++) {
        size_t m = bm + wm + (mi << 4) + (l4 << 2) + r;
        size_t n = bn + wn + (ni << 4) + l15;
        if (OUTBF16)
          ((u16*)Cout)[m * N + n] = f2bf(acc[mi][ni][r]);
        else
          ((float*)Cout)[m * N + n] = acc[mi][ni][r];
      }
}

// ---------------- fused RMSNorm + 2D RoPE (tiled, coalesced) ----------------
// C1 bf16 [4096][3456] -> Qp bf16 [h][n][96]  (pad 72..95 = 0),
//                         Kp bf16 [h][n][128] (granules 0..11 written; 12..15 unread pad),
//                         Vt bf16 [h][80][4096] (pad rows 72..79 = 0)
__global__ __launch_bounds__(256, 2) void norm_rope(
    const u16* __restrict__ C1, const float* __restrict__ cosv,
    const float* __restrict__ sinv, const float* __restrict__ qsc,
    const float* __restrict__ ksc, u16* __restrict__ Qp, u16* __restrict__ Kp,
    u16* __restrict__ Vt) {
  __shared__ __align__(16) u16 in_t[32 * 224];
  __shared__ __align__(16) u16 qo[32 * 96];
  __shared__ __align__(16) u16 ko[32 * 96];
  __shared__ __align__(16) u16 vo[80 * 48];
  const int tid = threadIdx.x;
  const int h = blockIdx.y;
  const int n0 = blockIdx.x * 32;

  // phase 1: cooperative load of the 32x216 tile (16B granules)
#pragma unroll
  for (int k = 0; k < 4; k++) {
    int g = tid + k * 256;
    if (g < 864) {
      int row = g / 27, j = g - row * 27;
      int seg = j / 9, c = (j - seg * 9) * 8;
      const u16* src = C1 + (size_t)(n0 + row) * 3456 + seg * 1152 + h * HD + c;
      *(uint4*)&in_t[row * 224 + j * 8] = *(const uint4*)src;
    }
  }
  __syncthreads();

  // phase 2: per-row (8 lanes/row) rms + rope + v-transpose
  const int r = tid >> 3, p = tid & 7;
  float sq = 0, sk = 0, sv = 0;
  auto acc8 = [&](int off, float& s) {
    uint4 v = *(const uint4*)&in_t[r * 224 + off];
    unsigned int vv[4] = {v.x, v.y, v.z, v.w};
#pragma unroll
    for (int q = 0; q < 4; q++) {
      float a = bf2f((u16)(vv[q] & 0xffff));
      float b = bf2f((u16)(vv[q] >> 16));
      s += a * a + b * b;
    }
  };
  acc8(0 + p * 8, sq);
  acc8(72 + p * 8, sk);
  acc8(144 + p * 8, sv);
  if (p == 0) { acc8(64, sq); acc8(136, sk); acc8(208, sv); }
#pragma unroll
  for (int m = 1; m < 8; m <<= 1) {
    sq += __shfl_xor(sq, m);
    sk += __shfl_xor(sk, m);
    sv += __shfl_xor(sv, m);
  }
  const float rq = rsqrtf(sq * (1.0f / 72.0f) + 1e-6f);
  const float rk = rsqrtf(sk * (1.0f / 72.0f) + 1e-6f);
  const float rv = rsqrtf(sv * (1.0f / 72.0f) + 1e-6f);

#pragma unroll
  for (int u = 0; u < 5; u++) {
    int ti = p + (u << 3);
    if (ti < 36) {
      int i1 = ti + ((ti >= 18) ? 18 : 0);
      int i2 = i1 + 18;
      const float* cb = cosv + (size_t)(n0 + r) * HD;
      const float* sb = sinv + (size_t)(n0 + r) * HD;
      float c1 = cb[i1], c2 = cb[i2], s1 = sb[i1], s2 = sb[i2];
      float q1 = bf2f(in_t[r * 224 + i1]) * rq * qsc[i1];
      float q2 = bf2f(in_t[r * 224 + i2]) * rq * qsc[i2];
      float k1 = bf2f(in_t[r * 224 + 72 + i1]) * rk * ksc[i1];
      float k2 = bf2f(in_t[r * 224 + 72 + i2]) * rk * ksc[i2];
      qo[r * 96 + i1] = f2bf(q1 * c1 - q2 * s1);
      qo[r * 96 + i2] = f2bf(q2 * c2 + q1 * s2);
      ko[r * 96 + i1] = f2bf(k1 * c1 - k2 * s1);
      ko[r * 96 + i2] = f2bf(k2 * c2 + k1 * s2);
    }
  }
#pragma unroll
  for (int u = 0; u < 9; u++) {
    int d = p * 9 + u;
    vo[d * 48 + r] = f2bf(bf2f(in_t[r * 224 + 144 + d]) * rv);
  }
  // zero pads: qo/ko granules 9..11 (cols 72..95)
  if (p < 3) {
    uint4 z = make_uint4(0, 0, 0, 0);
    *(uint4*)&qo[r * 96 + (9 + p) * 8] = z;
    *(uint4*)&ko[r * 96 + (9 + p) * 8] = z;
  }
  // zero pads: vo rows 72..79
  if (tid < 32) {
    int d = 72 + (tid >> 2), g = tid & 3;
    *(uint4*)&vo[d * 48 + g * 8] = make_uint4(0, 0, 0, 0);
  }
  __syncthreads();

  // phase 3: coalesced stores (32 rows x 12 granules = 384)
#pragma unroll
  for (int k = 0; k < 2; k++) {
    int g = tid + k * 256;
    if (g < 384) {
      int row = g / 12, j = g - row * 12;
      *(uint4*)(Qp + ((size_t)h * SEQ + n0 + row) * 96 + j * 8) = *(const uint4*)&qo[row * 96 + j * 8];
      *(uint4*)(Kp + ((size_t)h * SEQ + n0 + row) * 128 + j * 8) = *(const uint4*)&ko[row * 96 + j * 8];
    }
  }
#pragma unroll
  for (int k = 0; k < 2; k++) {
    int g = tid + k * 256;
    if (g < 320) {
      int d = g >> 2, j = g & 3;
      *(uint4*)(Vt + ((size_t)h * 80 + d) * SEQ + n0 + j * 8) = *(const uint4*)&vo[d * 48 + j * 8];
    }
  }
}

// ---------------- flash attention ----------------
// 512 threads = 8 waves x 16 q-rows (QBLK=128), 64-key tiles, dbuf, 1 barrier/tile.
// Q [h][n][96]; K [h][n][128] (XOR-swizzled staging over 16 granules); V [h][80][n].
// Head->XCD clustered block remap.
__global__ __launch_bounds__(512, 4) void attn(const u16* __restrict__ Qp,
                                               const u16* __restrict__ Kp,
                                               const u16* __restrict__ Vt,
                                               u16* __restrict__ AO) {
  __shared__ __align__(16) u16 Ks[2][64 * 128];  // 32 KB
  __shared__ __align__(16) u16 Vs[2][80 * 64];   // 20 KB
  __shared__ __align__(16) u16 Ps[8][16 * 64];   // 16 KB (per-wave P)
  const int tid = threadIdx.x;
  const int wave = tid >> 6, lane = tid & 63;
  const int l15 = lane & 15, l4 = lane >> 4;

  // head->XCD clustering: XCD = linear_bid % 8; put each head entirely on one XCD
  const int bid = blockIdx.x + (blockIdx.y << 5);
  const int h = ((bid & 7) << 1) | ((bid >> 3) & 1);
  const int qt = bid >> 4;  // 0..31
  const int q0 = qt * 128 + wave * 16;

  // Q fragment (B-operand: col q = l15, k-slice = kk*32 + l4*8)
  bf16x8 bq[3];
  const u16* qbase = Qp + ((size_t)h * SEQ + q0 + l15) * 96;
#pragma unroll
  for (int kk = 0; kk < 3; kk++) bq[kk] = *(const bf16x8*)(qbase + kk * 32 + l4 * 8);

  f32x4 acc[5] = {};
  float mi_ = -1e30f, li_ = 0.0f;

  auto stage = [&](int buf, int k0) {
    // K: 64 rows x 16 granules = 1024, source-swizzled (j ^ row&15), linear LDS dest
    {
      int m = tid >> 4, j = tid & 15;
      int js = j ^ (m & 15);
      gload_lds16(Kp + ((size_t)h * SEQ + k0 + m) * 128 + js * 8,
                  (void*)&Ks[buf][(size_t)(wave << 6) * 8]);
      int g2 = tid + 512;
      int m2 = g2 >> 4, j2 = g2 & 15;
      int js2 = j2 ^ (m2 & 15);
      gload_lds16(Kp + ((size_t)h * SEQ + k0 + m2) * 128 + js2 * 8,
                  (void*)&Ks[buf][(size_t)(512 + (wave << 6)) * 8]);
    }
    // V: 80 rows x 8 granules = 640, source-swizzled (j ^ d&7)
    {
      int d = tid >> 3, j = tid & 7;
      int js = j ^ (d & 7);
      gload_lds16(Vt + ((size_t)h * 80 + d) * SEQ + k0 + js * 8,
                  (void*)&Vs[buf][(size_t)(wave << 6) * 8]);
      if (wave < 2) {
        int g2 = tid + 512;
        int d2 = g2 >> 3, j2 = g2 & 7;
        int js2 = j2 ^ (d2 & 7);
        gload_lds16(Vt + ((size_t)h * 80 + d2) * SEQ + k0 + js2 * 8,
                    (void*)&Vs[buf][(size_t)(512 + (wave << 6)) * 8]);
      }
    }
  };

  stage(0, 0);
  for (int t = 0; t < 64; t++) {
    __syncthreads();  // tile t staged (vmcnt drained); buf t+1 free
    if (t < 63) stage((t + 1) & 1, (t + 1) * 64);
    const u16* Kb = Ks[t & 1];
    const u16* Vb = Vs[t & 1];

    // S^T = K * Q  (col q = l15, row k = nf*16 + l4*4 + r)
    f32x4 s[4] = {};
    __builtin_amdgcn_s_setprio(1);
#pragma unroll
    for (int kk = 0; kk < 3; kk++) {
      int slot = (kk << 2) + l4;
      bf16x8 ak[4];
#pragma unroll
      for (int nf = 0; nf < 4; nf++) {
        int row = (nf << 4) + l15;
        ak[nf] = *(const bf16x8*)&Kb[row * 128 + ((slot ^ l15) << 3)];
      }
#pragma unroll
      for (int nf = 0; nf < 4; nf++)
        s[nf] = __builtin_amdgcn_mfma_f32_16x16x32_bf16(ak[nf], bq[kk], s[nf], 0, 0, 0);
    }
    __builtin_amdgcn_s_setprio(0);

    // online softmax: lane owns 16 k-scores of q-column l15
    float v0 = fmaxf(fmaxf(s[0][0], s[0][1]), fmaxf(s[0][2], s[0][3]));
    float v1 = fmaxf(fmaxf(s[1][0], s[1][1]), fmaxf(s[1][2], s[1][3]));
    float v2 = fmaxf(fmaxf(s[2][0], s[2][1]), fmaxf(s[2][2], s[2][3]));
    float v3 = fmaxf(fmaxf(s[3][0], s[3][1]), fmaxf(s[3][2], s[3][3]));
    float v = fmaxf(fmaxf(v0, v1), fmaxf(v2, v3));
    v = fmaxf(v, __shfl_xor(v, 16));
    v = fmaxf(v, __shfl_xor(v, 32));
    float mnew = fmaxf(mi_, v);
    float scl = __expf(mi_ - mnew);
    mi_ = mnew;
    float rsum = 0.0f;
#pragma unroll
    for (int nf = 0; nf < 4; nf++) {
      ushort4 pk;
      float p0 = __expf(s[nf][0] - mnew);
      float p1 = __expf(s[nf][1] - mnew);
      float p2 = __expf(s[nf][2] - mnew);
      float p3 = __expf(s[nf][3] - mnew);
      rsum += (p0 + p1) + (p2 + p3);
      pk.x = f2bf(p0); pk.y = f2bf(p1); pk.z = f2bf(p2); pk.w = f2bf(p3);
      int gs = ((nf << 2) + l4) ^ ((l15 & 7) << 1);
      *(ushort4*)&Ps[wave][l15 * 64 + gs * 4] = pk;
    }
    li_ = li_ * scl + rsum;  // lane-partial sum; reduced in epilogue

    // rescale accumulator (acc row q = l4*4+r; scl lives at lane l15==q)
#pragma unroll
    for (int r = 0; r < 4; r++) {
      float sr = __shfl(scl, (l4 << 2) + r);
#pragma unroll
      for (int ni = 0; ni < 5; ni++) acc[ni][r] *= sr;
    }

    // PV: O[q][d] += P[q][k] * V[k][d]
    __builtin_amdgcn_s_setprio(1);
#pragma unroll
    for (int kk = 0; kk < 2; kk++) {
      int gb = ((kk << 3) + (l4 << 1)) ^ ((l15 & 7) << 1);
      bf16x8 pa = *(const bf16x8*)&Ps[wave][l15 * 64 + gb * 4];
      int slot = (kk << 2) + l4;
#pragma unroll
      for (int ni = 0; ni < 5; ni++) {
        int d = (ni << 4) + l15;
        bf16x8 bv = *(const bf16x8*)&Vb[d * 64 + ((slot ^ (d & 7)) << 3)];
        acc[ni] = __builtin_amdgcn_mfma_f32_16x16x32_bf16(pa, bv, acc[ni], 0, 0, 0);
      }
    }
    __builtin_amdgcn_s_setprio(0);
  }

  // epilogue: finish row-sum reduce, normalize, store
  li_ += __shfl_xor(li_, 16);
  li_ += __shfl_xor(li_, 32);
#pragma unroll
  for (int r = 0; r < 4; r++) {
    float inv = 1.0f / __shfl(li_, (l4 << 2) + r);
    int q = q0 + (l4 << 2) + r;
#pragma unroll
    for (int ni = 0; ni < 5; ni++) {
      int d = (ni << 4) + l15;
      if (d < HD) AO[(size_t)q * HID + h * HD + d] = f2bf(acc[ni][r] * inv);
    }
  }
}

extern "C" void kernel_launch(void* const* d_in, const int* in_sizes, int n_in,
                              void* d_out, int out_size, void* d_ws, size_t ws_size,
                              hipStream_t stream) {
  const float* X = (const float*)d_in[0];
  const float* cosv = (const float*)d_in[1];
  const float* sinv = (const float*)d_in[2];
  const float* Wq = (const float*)d_in[3];
  const float* Wk = (const float*)d_in[4];
  const float* Wv = (const float*)d_in[5];
  const float* Wo = (const float*)d_in[6];
  const float* qsc = (const float*)d_in[7];
  const float* ksc = (const float*)d_in[8];
  float* out = (float*)d_out;

  uint8_t* ws = (uint8_t*)d_ws;
  u16* Xb  = (u16*)(ws);                 //  9,437,184 B  (4096x1152 bf16)
  u16* Wt  = (u16*)(ws + 9437184);       //  7,962,624 B  (3456x1152 bf16)
  u16* Wot = (u16*)(ws + 17399808);      //  2,654,208 B  (1152x1152 bf16)
  u16* C1  = (u16*)(ws + 20054016);      // 28,311,552 B  (4096x3456 bf16)
  u16* Qp  = (u16*)(ws + 48365568);      // 12,582,912 B  (16x4096x96 bf16)
  u16* Kp  = (u16*)(ws + 60948480);      // 16,777,216 B  (16x4096x128 bf16, padded)
  u16* Vt  = (u16*)(ws + 77725696);      // 10,485,760 B  (16x80x4096 bf16)
  u16* AO  = Xb;                         // reuse: Xb consumed by GEMM1 before attn writes

  cvt_x<<<4608, 256, 0, stream>>>(X, Xb, (SEQ * HID) / 4);
  transpose_w<<<dim3(36, 36, 4), 256, 0, stream>>>(Wq, Wk, Wv, Wo, Wt, Wot);
  gemm_bt<1><<<dim3(32, 27), 256, 0, stream>>>(Xb, Wt, (void*)C1, SEQ, 3456, HID);
  norm_rope<<<dim3(128, 16), 256, 0, stream>>>(C1, cosv, sinv, qsc, ksc, Qp, Kp, Vt);
  attn<<<dim3(32, 16), 512, 0, stream>>>(Qp, Kp, Vt, AO);
  gemm_bt<0><<<dim3(32, 9), 256, 0, stream>>>(AO, Wot, (void*)out, SEQ, HID, HID);
}